// Round 5
// baseline (404.347 us; speedup 1.0000x reference)
//
#include <hip/hip_runtime.h>

#define T_STEPS 4096
#define BATCH   2048
#define HID     10
#define UB      16   // steps per buffer; outer loop advances 2*UB (ping-pong)

// ---- R7/R8-proven load skeleton ------------------------------------------
__device__ __forceinline__ void issue16(float (&xr)[UB], const float* base) {
#pragma unroll
    for (int u = 0; u < UB; ++u)
        asm volatile("global_load_dword %0, %1, off"
                     : "=v"(xr[u]) : "v"(base + (size_t)u * BATCH) : "memory");
}
#define BIND16(a) "+v"(a[0]),"+v"(a[1]),"+v"(a[2]),"+v"(a[3]),"+v"(a[4]), \
    "+v"(a[5]),"+v"(a[6]),"+v"(a[7]),"+v"(a[8]),"+v"(a[9]),"+v"(a[10]),   \
    "+v"(a[11]),"+v"(a[12]),"+v"(a[13]),"+v"(a[14]),"+v"(a[15])
__device__ __forceinline__ void wait1_bind(float (&xr)[UB]) {
    asm volatile("s_waitcnt vmcnt(1)" : BIND16(xr) :: "memory");
}
__device__ __forceinline__ void wait0_bind(float (&xr)[UB]) {
    asm volatile("s_waitcnt vmcnt(0)" : BIND16(xr) :: "memory");
}

// ---- R13: broadcast-basis step -------------------------------------------
// R12 post-mortem: clock-governor hypothesis refuted. Two issue-cost models
// remain: A) DPP~5cyc / plain~2 / trans~8, B) uniform ~4cyc wave cadence.
// This step discriminates them: replace the 16-op ROTATION basis (15 DPP+1)
// with a 10-op BROADCAST basis — ds_swizzle_b32 BitMode and=0x10,or=k
// broadcasts lane k within each 16-lane group (upper 32-half identical), and
// each lane FMAs r[k] against its own weight wv[k]=-2C*W_hh[j][k] (lane 10:
// -2*wo[k], output row rides along as in R10). Mixed bases can't beat 10
// (mod-16 wraparound forces >=11 rotations for any uncovered k).
// ds_swizzle: lane-permute via LDS crossbar, no LDS storage, lgkmcnt,
// in-order returns -> grouped waits lgkmcnt(5)/lgkmcnt(0).
// Tail mirrors R10's proven spacing exactly: exp reads c at dist 1, s_nop,
// add, pk at dist 4 from final c, rcp at dist 2 from add, s_nop.
// Entry: r = r_t. Exit: r = r_{t+1}.
#define STEP_HEAD \
    "ds_swizzle_b32 %[b0], %[r] offset:0x10\n\t"   /* bcast lane 0  */ \
    "ds_swizzle_b32 %[b1], %[r] offset:0x30\n\t"   /* bcast lane 1  */ \
    "ds_swizzle_b32 %[b2], %[r] offset:0x50\n\t"   /* bcast lane 2  */ \
    "ds_swizzle_b32 %[b3], %[r] offset:0x70\n\t"   /* bcast lane 3  */ \
    "ds_swizzle_b32 %[b4], %[r] offset:0x90\n\t"   /* bcast lane 4  */ \
    "ds_swizzle_b32 %[b5], %[r] offset:0xB0\n\t"   /* bcast lane 5  */ \
    "ds_swizzle_b32 %[b6], %[r] offset:0xD0\n\t"   /* bcast lane 6  */ \
    "ds_swizzle_b32 %[b7], %[r] offset:0xF0\n\t"   /* bcast lane 7  */ \
    "ds_swizzle_b32 %[b8], %[r] offset:0x110\n\t"  /* bcast lane 8  */ \
    "ds_swizzle_b32 %[b9], %[r] offset:0x130\n\t"  /* bcast lane 9  */ \
    "v_fma_f32 %[c], %[wih2], %[x], %[bj2]\n\t"    /* r-indep seed, fills latency */ \
    "s_waitcnt lgkmcnt(5)\n\t"                     /* b0..b4 returned (in-order) */ \
    "v_fmac_f32 %[c], %[b0], %[w0]\n\t" \
    "v_fmac_f32 %[c], %[b1], %[w1]\n\t" \
    "v_fmac_f32 %[c], %[b2], %[w2]\n\t" \
    "v_fmac_f32 %[c], %[b3], %[w3]\n\t" \
    "v_fmac_f32 %[c], %[b4], %[w4]\n\t" \
    "s_waitcnt lgkmcnt(0)\n\t"                     /* b5..b9 returned */ \
    "v_fmac_f32 %[c], %[b5], %[w5]\n\t" \
    "v_fmac_f32 %[c], %[b6], %[w6]\n\t" \
    "v_fmac_f32 %[c], %[b7], %[w7]\n\t" \
    "v_fmac_f32 %[c], %[b8], %[w8]\n\t" \
    "v_fmac_f32 %[c], %[b9], %[w9]\n\t" \
    "v_exp_f32 %[ex], %[c]\n\t"                    /* c dist1 (R8/R10-proven) */ \
    "s_nop 0\n\t"                                  /* trans-use wait state */ \
    "v_add_f32 %[ex], 1.0, %[ex]\n\t"

#define STEP_TAIL \
    "v_rcp_f32 %[r], %[ex]\n\t"                    /* ex dist2 (R10-proven) */ \
    "s_nop 0"                                      /* trans-use wait state */

// pk extraction (between add and rcp, c dist 4 from final fmac — R10-proven):
// lane u-1 <- lane 10's c via row_ror:(u+5)&15.
#define PKDPP(N) "v_fmac_f32_dpp %[pk], %[c], %[m] row_ror:" #N " row_mask:0xf bank_mask:0xf\n\t"
#define PKPLAIN  "v_fmac_f32 %[pk], %[c], %[m]\n\t"

#define DEF_STEP(SUF, PKLINE_) \
__device__ __forceinline__ void step_##SUF(float& r, float& pk, float x, \
        float wih2, float bj2, float m, const float (&w)[10]) { \
    float b0, b1, b2, b3, b4, b5, b6, b7, b8, b9, c, ex; \
    asm volatile( STEP_HEAD PKLINE_ STEP_TAIL \
        : [b0]"=&v"(b0), [b1]"=&v"(b1), [b2]"=&v"(b2), [b3]"=&v"(b3), \
          [b4]"=&v"(b4), [b5]"=&v"(b5), [b6]"=&v"(b6), [b7]"=&v"(b7), \
          [b8]"=&v"(b8), [b9]"=&v"(b9), [c]"=&v"(c), [ex]"=&v"(ex), \
          [r]"+v"(r), [pk]"+v"(pk) \
        : [x]"v"(x), [wih2]"v"(wih2), [bj2]"v"(bj2), [m]"v"(m), \
          [w0]"v"(w[0]), [w1]"v"(w[1]), [w2]"v"(w[2]), [w3]"v"(w[3]), \
          [w4]"v"(w[4]), [w5]"v"(w[5]), [w6]"v"(w[6]), [w7]"v"(w[7]), \
          [w8]"v"(w[8]), [w9]"v"(w[9])); \
}

DEF_STEP(r0,  PKPLAIN)
DEF_STEP(r1,  PKDPP(1))
DEF_STEP(r2,  PKDPP(2))
DEF_STEP(r3,  PKDPP(3))
DEF_STEP(r4,  PKDPP(4))
DEF_STEP(r6,  PKDPP(6))
DEF_STEP(r7,  PKDPP(7))
DEF_STEP(r8,  PKDPP(8))
DEF_STEP(r9,  PKDPP(9))
DEF_STEP(r10, PKDPP(10))
DEF_STEP(r11, PKDPP(11))
DEF_STEP(r12, PKDPP(12))
DEF_STEP(r13, PKDPP(13))
DEF_STEP(r14, PKDPP(14))
DEF_STEP(r15, PKDPP(15))

// Dispatcher: blob u extracts row t0+u-1 -> lane u-1 needs ror (u+5)&15.
// U=0 (mask 0) falls through to r15 — extraction value irrelevant (R10-proven).
template<int U>
__device__ __forceinline__ void step_u(float& r, float& pk, float x,
                                       float wih2, float bj2,
                                       const float (&km)[16], float mz,
                                       const float (&w)[10]) {
    constexpr int ROT = (U + 5) & 15;
    float m;
    if constexpr (U == 0) m = mz; else m = km[U - 1];
    if constexpr (ROT == 0)       step_r0 (r, pk, x, wih2, bj2, m, w);
    else if constexpr (ROT == 1)  step_r1 (r, pk, x, wih2, bj2, m, w);
    else if constexpr (ROT == 2)  step_r2 (r, pk, x, wih2, bj2, m, w);
    else if constexpr (ROT == 3)  step_r3 (r, pk, x, wih2, bj2, m, w);
    else if constexpr (ROT == 4)  step_r4 (r, pk, x, wih2, bj2, m, w);
    else if constexpr (ROT == 6)  step_r6 (r, pk, x, wih2, bj2, m, w);
    else if constexpr (ROT == 7)  step_r7 (r, pk, x, wih2, bj2, m, w);
    else if constexpr (ROT == 8)  step_r8 (r, pk, x, wih2, bj2, m, w);
    else if constexpr (ROT == 9)  step_r9 (r, pk, x, wih2, bj2, m, w);
    else if constexpr (ROT == 10) step_r10(r, pk, x, wih2, bj2, m, w);
    else if constexpr (ROT == 11) step_r11(r, pk, x, wih2, bj2, m, w);
    else if constexpr (ROT == 12) step_r12(r, pk, x, wih2, bj2, m, w);
    else if constexpr (ROT == 13) step_r13(r, pk, x, wih2, bj2, m, w);
    else if constexpr (ROT == 14) step_r14(r, pk, x, wih2, bj2, m, w);
    else                          step_r15(r, pk, x, wih2, bj2, m, w);
}

template<int U>
__device__ __forceinline__ void run16(float& r, float& pk, const float (&xr)[UB],
                                      float wih2, float bj2,
                                      const float (&km)[16], float mz,
                                      const float (&w)[10]) {
    if constexpr (U < UB) {
        step_u<U>(r, pk, xr[U], wih2, bj2, km, mz, w);
        run16<U + 1>(r, pk, xr, wih2, bj2, km, mz, w);
    }
}

// Block-end finisher: seed from final r (row t0+15) and reduce. s_nop 1
// covers DPP read-after-write hazards (R8-proven).
__device__ __forceinline__ void finish_reduce(float r, float& p, float& pk,
                                              float wo2, float m15) {
    asm volatile(
        "v_mul_f32 %[p], %[wo2], %[r]\n\t"
        "s_nop 1\n\t"
        "v_add_f32_dpp %[p], %[p], %[p] row_ror:8 row_mask:0xf bank_mask:0xf\n\t"
        "s_nop 1\n\t"
        "v_add_f32_dpp %[p], %[p], %[p] row_ror:4 row_mask:0xf bank_mask:0xf\n\t"
        "s_nop 1\n\t"
        "v_add_f32_dpp %[p], %[p], %[p] row_ror:2 row_mask:0xf bank_mask:0xf\n\t"
        "s_nop 1\n\t"
        "v_add_f32_dpp %[p], %[p], %[p] row_ror:1 row_mask:0xf bank_mask:0xf\n\t"
        "s_nop 1\n\t"
        "v_fmac_f32 %[pk], %[p], %[m]"
        : [p]"+v"(p), [pk]"+v"(pk)
        : [r]"v"(r), [wo2]"v"(wo2), [m]"v"(m15));
}

__global__ __launch_bounds__(64, 1) void rnn_kernel(
    const float* __restrict__ x,
    const float* __restrict__ h0,
    const float* __restrict__ W_ih,
    const float* __restrict__ b_ih,
    const float* __restrict__ W_hh,
    const float* __restrict__ b_hh,
    const float* __restrict__ W_out,
    const float* __restrict__ b_out,
    float* __restrict__ out)
{
    const int tid = threadIdx.x;            // 0..63
    const int j   = tid & 15;               // lane-in-group; j<10 owns dim j
    const int b   = (blockIdx.x << 2) + (tid >> 4);
    const bool jv = (j < HID);
    const int jc  = jv ? j : 0;

    const float CC = 2.88539008177792681472f;   // 2*log2(e)

    // Raw per-lane weights (idle lanes zero).
    const float wih = jv ? W_ih[jc] : 0.0f;
    const float bj  = jv ? (b_ih[jc] + b_hh[jc]) : 0.0f;
    const float wo  = jv ? W_out[jc] : 0.0f;

    // Broadcast-basis weights: wv[k] = coefficient of r[k] for this lane.
    // Lanes 0..9: -2C*W_hh[j][k] (r-form). Lane 10: output row, unscaled
    // (-2*wo[k]) so its c = y - C0. Lanes 11..15: 0.
    float wsum = 0.0f;
    float wv[10];
#pragma unroll
    for (int k = 0; k < HID; ++k) {
        const float whh = jv ? W_hh[jc * HID + k] : 0.0f;
        wsum += whh;
        if (jv)            wv[k] = -2.0f * CC * whh;
        else if (j == 10)  wv[k] = -2.0f * W_out[k];
        else               wv[k] = 0.0f;
    }

    // r-form folded constants: a' = C*a with h = 1-2r absorbed.
    const float wih2 = CC * wih;                 // 0 for j>=10
    const float bj2  = CC * (bj + wsum);         // 0 for j>=10
    const float wo2  = -2.0f * wo;               // finisher only
    float c0sum = b_out[0];
#pragma unroll
    for (int k = 0; k < HID; ++k) c0sum += W_out[k];   // C0 = sum(wo) + bo

    // Keep-masks.
    float km[16];
#pragma unroll
    for (int i = 0; i < 16; ++i) km[i] = (j == i) ? 1.0f : 0.0f;
    const float mzero = 0.0f;

    // r_0 = (1 - h_0)/2 ; idle lanes h0=0 -> r=0.5 (their fixed point).
    float rval = fmaf(-0.5f, jv ? h0[b * HID + jc] : 0.0f, 0.5f);
    float p = 0.0f, pk = 0.0f;

    const float* xb = x + b;
    float xA[UB], xB[UB];

    issue16(xA, xb);
    wait0_bind(xA);

    for (int t0 = 0; t0 < T_STEPS; t0 += 2 * UB) {
        // ---- half 1: consume xA, prefetch xB ----
        wait1_bind(xA);
        issue16(xB, xb + (size_t)(t0 + UB) * BATCH);
        run16<0>(rval, pk, xA, wih2, bj2, km, mzero, wv);
        finish_reduce(rval, p, pk, wo2, km[15]);
        out[(size_t)(t0 + j) * BATCH + b] = pk + c0sum;
        pk = 0.0f;

        // ---- half 2: consume xB, prefetch xA ----
        wait1_bind(xB);
        const float* xsrc = (t0 + 2 * UB < T_STEPS)
                          ? (xb + (size_t)(t0 + 2 * UB) * BATCH) : xb;
        issue16(xA, xsrc);
        run16<0>(rval, pk, xB, wih2, bj2, km, mzero, wv);
        finish_reduce(rval, p, pk, wo2, km[15]);
        out[(size_t)(t0 + UB + j) * BATCH + b] = pk + c0sum;
        pk = 0.0f;
    }

    // Drain the final speculative xA reload while registers are still bound
    // (async-clobber hazard, R6 post-mortem).
    wait0_bind(xA);

    // h_last: h = 1 - 2r
    if (jv) out[(size_t)T_STEPS * BATCH + (size_t)b * HID + j]
                = fmaf(-2.0f, rval, 1.0f);
}

extern "C" void kernel_launch(void* const* d_in, const int* in_sizes, int n_in,
                              void* d_out, int out_size, void* d_ws, size_t ws_size,
                              hipStream_t stream) {
    const float* x     = (const float*)d_in[0];
    const float* h0    = (const float*)d_in[1];
    const float* W_ih  = (const float*)d_in[2];
    const float* b_ih  = (const float*)d_in[3];
    const float* W_hh  = (const float*)d_in[4];
    const float* b_hh  = (const float*)d_in[5];
    const float* W_out = (const float*)d_in[6];
    const float* b_out = (const float*)d_in[7];

    rnn_kernel<<<BATCH / 4, 64, 0, stream>>>(
        x, h0, W_ih, b_ih, W_hh, b_hh, W_out, b_out, (float*)d_out);
}

// Round 6
// 369.773 us; speedup vs baseline: 1.0935x; 1.0935x over previous
//
#include <hip/hip_runtime.h>

#define T_STEPS 4096
#define BATCH   2048
#define HID     10

// ---- R14: half-split rotation scheme --------------------------------------
// Model (fit R8-R13): wall/step = #VALU*2.58ns + #ds*4.2ns; nops/waits ~free;
// DPP == plain VALU; dependency depth irrelevant. So: minimize weighted ops.
// Layout: 32 lanes per batch (rows r0,r1 = batch0; r2,r3 = batch1).
//   even rows (0,2): hold r identity; compute eff rotations 0-7 via ror:0-7.
//   odd rows (1,3): hold s[j]=r[(j+8)&15]; the SAME ror:0-7 delivers
//     s[(j-N)&15] = r[(j+8-N)&15] -> eff rotations 8-15 (per-lane weights).
// ds_swizzle xor16 (offset 0x401F) swaps the two half-sums within each
// 32-group -> both rows get total a'[j]. Odd-row pre-rotation is maintained
// by rotating the PRE-rcp value in place: v_mov_b32_dpp e,e ror:8 mask 0xA
// (rotation commutes with per-lane rcp; xor8 == +8 mod 16).
// Output row rides on lane 10 of both rows (split 7+3 coverage), extracted
// by one fmac_dpp per step as in R10. Wrap-extraction (u=0 uses km[15])
// eliminates the per-16 finisher; final y done once after the loop.
// x prefetch: per-step ring load (slot u feeds step u+16), vmcnt(14) before
// consuming -- the load+wait+fma also give the swizzle 4 slots of cover.

#define PKDPP(N) "v_fmac_f32_dpp %[pk], %[a], %[m] row_ror:" #N " row_mask:0xf bank_mask:0xf\n\t"
#define PKPLAIN  "v_fmac_f32 %[pk], %[a], %[m]\n\t"

// Hazard spacings (all proven in R8-R13): rcp->plain-r dist2+nop (R9),
// rcp->DPP-r dist3+nop (R9), c->exp dist1 (R10), exp->add1 dist2 (R10),
// add1->rcp dist2 (R10), VALU->DPP-read dist3 (R8), a->pk-DPP dist4 (R10),
// DS-read operand interlock (R13).
#define STEP_BODY(PKLINE_) \
    "v_fmac_f32 %[c], %[r], %[w0]\n\t"                                           \
    "v_mul_f32_dpp %[d], %[r], %[w1] row_ror:1 row_mask:0xf bank_mask:0xf\n\t"   \
    "v_fmac_f32_dpp %[c], %[r], %[w2] row_ror:2 row_mask:0xf bank_mask:0xf\n\t"  \
    "v_fmac_f32_dpp %[d], %[r], %[w3] row_ror:3 row_mask:0xf bank_mask:0xf\n\t"  \
    "v_fmac_f32_dpp %[c], %[r], %[w4] row_ror:4 row_mask:0xf bank_mask:0xf\n\t"  \
    "v_fmac_f32_dpp %[d], %[r], %[w5] row_ror:5 row_mask:0xf bank_mask:0xf\n\t"  \
    "v_fmac_f32_dpp %[c], %[r], %[w6] row_ror:6 row_mask:0xf bank_mask:0xf\n\t"  \
    "v_fmac_f32_dpp %[d], %[r], %[w7] row_ror:7 row_mask:0xf bank_mask:0xf\n\t"  \
    "v_add_f32 %[o], %[c], %[d]\n\t"                                             \
    "s_waitcnt vmcnt(14)\n\t"                                                    \
    "ds_swizzle_b32 %[q], %[o] offset:0x401F\n\t"                                \
    "v_fma_f32 %[c], %[wih2], %[xn], %[bj2]\n\t"                                 \
    "global_load_dword %[xl], %[voff], %[xs]\n\t"                                \
    "v_add_u32 %[voff], 0x2000, %[voff]\n\t"                                     \
    "s_waitcnt lgkmcnt(0)\n\t"                                                   \
    "v_add_f32 %[a], %[o], %[q]\n\t"                                             \
    "v_exp_f32 %[e], %[a]\n\t"                                                   \
    "s_nop 0\n\t"                                                                \
    "v_add_f32 %[e], 1.0, %[e]\n\t"                                              \
    PKLINE_                                                                      \
    "s_nop 0\n\t"                                                                \
    "v_mov_b32_dpp %[e], %[e] row_ror:8 row_mask:0xa bank_mask:0xf\n\t"          \
    "s_nop 0\n\t"                                                                \
    "v_rcp_f32 %[r], %[e]\n\t"                                                   \
    "s_nop 0"

#define DEF_STEP(SUF, PKLINE_) \
__device__ __forceinline__ void step_##SUF(float& r, float& c, float& pk, \
        unsigned& voff, float& xl, float xn, float wih2, float bj2, float m, \
        const float (&w)[8], const float* xs) { \
    float d, o, q, a, e; \
    asm volatile( STEP_BODY(PKLINE_) \
        : [r]"+v"(r), [c]"+v"(c), [pk]"+v"(pk), [voff]"+v"(voff), [xl]"+v"(xl), \
          [d]"=&v"(d), [o]"=&v"(o), [q]"=&v"(q), [a]"=&v"(a), [e]"=&v"(e) \
        : [xn]"v"(xn), [wih2]"v"(wih2), [bj2]"v"(bj2), [m]"v"(m), \
          [w0]"v"(w[0]), [w1]"v"(w[1]), [w2]"v"(w[2]), [w3]"v"(w[3]), \
          [w4]"v"(w[4]), [w5]"v"(w[5]), [w6]"v"(w[6]), [w7]"v"(w[7]), \
          [xs]"s"(xs) \
        : "memory"); \
}

DEF_STEP(r0,  PKPLAIN)
DEF_STEP(r1,  PKDPP(1))
DEF_STEP(r2,  PKDPP(2))
DEF_STEP(r3,  PKDPP(3))
DEF_STEP(r4,  PKDPP(4))
DEF_STEP(r5,  PKDPP(5))
DEF_STEP(r6,  PKDPP(6))
DEF_STEP(r7,  PKDPP(7))
DEF_STEP(r8,  PKDPP(8))
DEF_STEP(r9,  PKDPP(9))
DEF_STEP(r10, PKDPP(10))
DEF_STEP(r11, PKDPP(11))
DEF_STEP(r12, PKDPP(12))
DEF_STEP(r13, PKDPP(13))
DEF_STEP(r14, PKDPP(14))
DEF_STEP(r15, PKDPP(15))

// Dispatcher: step U extracts out-row t0+U-1 to lane (U-1)&15 via
// ROT=(U+5)&15 (R10-proven); U=0 wraps (km[15] -> y_{t0-1}, no finisher).
// Ring: consume xv[(U+1)&15] (seed for step U+1), reload xv[U] (step U+16).
template<int U>
__device__ __forceinline__ void step_u(float& r, float& c, float& pk,
                                       unsigned& voff, float (&xv)[16],
                                       float wih2, float bj2,
                                       const float (&km)[16],
                                       const float (&w)[8], const float* xs) {
    constexpr int ROT = (U + 5) & 15;
    const float m = km[(U + 15) & 15];
    float& xl = xv[U];
    const float xn = xv[(U + 1) & 15];
    if constexpr (ROT == 0)       step_r0 (r, c, pk, voff, xl, xn, wih2, bj2, m, w, xs);
    else if constexpr (ROT == 1)  step_r1 (r, c, pk, voff, xl, xn, wih2, bj2, m, w, xs);
    else if constexpr (ROT == 2)  step_r2 (r, c, pk, voff, xl, xn, wih2, bj2, m, w, xs);
    else if constexpr (ROT == 3)  step_r3 (r, c, pk, voff, xl, xn, wih2, bj2, m, w, xs);
    else if constexpr (ROT == 4)  step_r4 (r, c, pk, voff, xl, xn, wih2, bj2, m, w, xs);
    else if constexpr (ROT == 5)  step_r5 (r, c, pk, voff, xl, xn, wih2, bj2, m, w, xs);
    else if constexpr (ROT == 6)  step_r6 (r, c, pk, voff, xl, xn, wih2, bj2, m, w, xs);
    else if constexpr (ROT == 7)  step_r7 (r, c, pk, voff, xl, xn, wih2, bj2, m, w, xs);
    else if constexpr (ROT == 8)  step_r8 (r, c, pk, voff, xl, xn, wih2, bj2, m, w, xs);
    else if constexpr (ROT == 9)  step_r9 (r, c, pk, voff, xl, xn, wih2, bj2, m, w, xs);
    else if constexpr (ROT == 10) step_r10(r, c, pk, voff, xl, xn, wih2, bj2, m, w, xs);
    else if constexpr (ROT == 11) step_r11(r, c, pk, voff, xl, xn, wih2, bj2, m, w, xs);
    else if constexpr (ROT == 12) step_r12(r, c, pk, voff, xl, xn, wih2, bj2, m, w, xs);
    else if constexpr (ROT == 13) step_r13(r, c, pk, voff, xl, xn, wih2, bj2, m, w, xs);
    else if constexpr (ROT == 14) step_r14(r, c, pk, voff, xl, xn, wih2, bj2, m, w, xs);
    else                          step_r15(r, c, pk, voff, xl, xn, wih2, bj2, m, w, xs);
}

template<int U>
__device__ __forceinline__ void run16(float& r, float& c, float& pk,
                                      unsigned& voff, float (&xv)[16],
                                      float wih2, float bj2,
                                      const float (&km)[16],
                                      const float (&w)[8], const float* xs) {
    if constexpr (U < 16) {
        step_u<U>(r, c, pk, voff, xv, wih2, bj2, km, w, xs);
        run16<U + 1>(r, c, pk, voff, xv, wih2, bj2, km, w, xs);
    }
}

#define BIND16(a) "+v"(a[0]),"+v"(a[1]),"+v"(a[2]),"+v"(a[3]),"+v"(a[4]), \
    "+v"(a[5]),"+v"(a[6]),"+v"(a[7]),"+v"(a[8]),"+v"(a[9]),"+v"(a[10]),   \
    "+v"(a[11]),"+v"(a[12]),"+v"(a[13]),"+v"(a[14]),"+v"(a[15])
__device__ __forceinline__ void wait0_bind(float (&xr)[16]) {
    asm volatile("s_waitcnt vmcnt(0)" : BIND16(xr) :: "memory");
}

// Final-step finisher (R8-proven): per-row 16-lane reduce of -2*wo.r.
__device__ __forceinline__ void finish_reduce(float r, float& p, float& pk,
                                              float wo2, float m0) {
    asm volatile(
        "v_mul_f32 %[p], %[wo2], %[r]\n\t"
        "s_nop 1\n\t"
        "v_add_f32_dpp %[p], %[p], %[p] row_ror:8 row_mask:0xf bank_mask:0xf\n\t"
        "s_nop 1\n\t"
        "v_add_f32_dpp %[p], %[p], %[p] row_ror:4 row_mask:0xf bank_mask:0xf\n\t"
        "s_nop 1\n\t"
        "v_add_f32_dpp %[p], %[p], %[p] row_ror:2 row_mask:0xf bank_mask:0xf\n\t"
        "s_nop 1\n\t"
        "v_add_f32_dpp %[p], %[p], %[p] row_ror:1 row_mask:0xf bank_mask:0xf\n\t"
        "s_nop 1\n\t"
        "v_fmac_f32 %[pk], %[p], %[m]"
        : [p]"+v"(p), [pk]"+v"(pk)
        : [r]"v"(r), [wo2]"v"(wo2), [m]"v"(m0));
}

__global__ __launch_bounds__(64, 1) void rnn_kernel(
    const float* __restrict__ x,
    const float* __restrict__ h0,
    const float* __restrict__ W_ih,
    const float* __restrict__ b_ih,
    const float* __restrict__ W_hh,
    const float* __restrict__ b_hh,
    const float* __restrict__ W_out,
    const float* __restrict__ b_out,
    float* __restrict__ out)
{
    const int tid  = threadIdx.x;                 // 0..63
    const int j    = tid & 15;                    // lane-in-row
    const bool ev  = !(tid & 16);                 // even rows (0,2): identity r
    const int b    = (blockIdx.x << 1) + (tid >> 5);   // rows 0,1 -> b; 2,3 -> b+1

    const float CC = 2.88539008177792681472f;     // 2*log2(e)

    // Rotation weights: 8 per lane. Even lane j, ror:N -> k=(j-N)&15 (eff 0-7).
    // Odd lane j, ror:N -> k=(j+8-N)&15 (eff 8-15). Row j<10: -2C*W_hh[j][k];
    // row j==10 (output): -2*W_out[k] (unscaled); else 0.
    float w[8];
#pragma unroll
    for (int N = 0; N < 8; ++N) {
        const int k = ev ? ((j - N) & 15) : ((j + 8 - N) & 15);
        float val = 0.0f;
        if (j < HID && k < HID)        val = -2.0f * CC * W_hh[j * HID + k];
        else if (j == 10 && k < HID)   val = -2.0f * W_out[k];
        w[N] = val;
    }
    // Bias fold (full row-sum; only on even rows so it's counted once).
    float wsum = 0.0f;
    if (j < HID) {
#pragma unroll
        for (int k = 0; k < HID; ++k) wsum += W_hh[j * HID + k];
    }
    const float wih2 = (ev && j < HID) ? CC * W_ih[j] : 0.0f;
    const float bj2  = (ev && j < HID) ? CC * (b_ih[j] + b_hh[j] + wsum) : 0.0f;
    const float wo2  = (ev && j < HID) ? (-2.0f * W_out[j]) : 0.0f;   // finisher
    float c0sum = b_out[0];
#pragma unroll
    for (int k = 0; k < HID; ++k) c0sum += W_out[k];   // C0 = sum(wo) + bo

    // Keep-masks (even rows only).
    float km[16];
#pragma unroll
    for (int i = 0; i < 16; ++i) km[i] = (ev && j == i) ? 1.0f : 0.0f;

    // r init: even lanes r[j]; odd lanes s[j]=r[(j+8)&15]. Invalid -> 0.5.
    const int kini = ev ? j : ((j + 8) & 15);
    float r = (kini < HID) ? fmaf(-0.5f, h0[b * HID + kini], 0.5f) : 0.5f;
    float pk = 0.0f;

    // x ring prime: load x[0..15]; voff = byte offset (t*BATCH + b)*4.
    const unsigned voff0 = (unsigned)b * 4u;
    unsigned voff = voff0;
    float xv[16];
#pragma unroll
    for (int u = 0; u < 16; ++u) {
        asm volatile("global_load_dword %0, %1, %2"
                     : "=v"(xv[u]) : "v"(voff), "s"(x) : "memory");
        voff += 8192u;
    }
    wait0_bind(xv);                 // voff now at t=16
    float c = fmaf(wih2, xv[0], bj2);   // seed for step 0

    for (int t0 = 0; t0 < T_STEPS; t0 += 16) {
        if (t0 + 16 >= T_STEPS) voff = voff0;   // last block: harmless reloads
        run16<0>(r, c, pk, voff, xv, wih2, bj2, km, w, x);
        // Store: lane j holds y_{t0+j} (j<15); lane15 holds y_{t0-1} (wrap).
        if (ev) {
            const int tj = t0 + ((j == 15) ? -1 : j);
            if (tj >= 0) out[(size_t)tj * BATCH + b] = pk + c0sum;
        }
        pk = 0.0f;
    }

    // Drain speculative ring reloads while regs are bound (R6 hazard).
    wait0_bind(xv);

    // Final output row t=4095 from final r (even rows, identity layout).
    float p = 0.0f, pk2 = 0.0f;
    finish_reduce(r, p, pk2, wo2, km[0]);
    if (ev && j == 0) out[(size_t)(T_STEPS - 1) * BATCH + b] = pk2 + c0sum;

    // h_last: h = 1 - 2r (even rows).
    if (ev && j < HID)
        out[(size_t)T_STEPS * BATCH + (size_t)b * HID + j] = fmaf(-2.0f, r, 1.0f);
}

extern "C" void kernel_launch(void* const* d_in, const int* in_sizes, int n_in,
                              void* d_out, int out_size, void* d_ws, size_t ws_size,
                              hipStream_t stream) {
    const float* x     = (const float*)d_in[0];
    const float* h0    = (const float*)d_in[1];
    const float* W_ih  = (const float*)d_in[2];
    const float* b_ih  = (const float*)d_in[3];
    const float* W_hh  = (const float*)d_in[4];
    const float* b_hh  = (const float*)d_in[5];
    const float* W_out = (const float*)d_in[6];
    const float* b_out = (const float*)d_in[7];

    rnn_kernel<<<BATCH / 2, 64, 0, stream>>>(
        x, h0, W_ih, b_ih, W_hh, b_hh, W_out, b_out, (float*)d_out);
}

// Round 7
// 324.543 us; speedup vs baseline: 1.2459x; 1.1394x over previous
//
#include <hip/hip_runtime.h>

#define T_STEPS 4096
#define BATCH   2048
#define HID     10
#define UB      16   // steps per buffer; outer loop advances 2*UB (ping-pong)

// ---- R7/R8-proven load skeleton ------------------------------------------
__device__ __forceinline__ void issue16(float (&xr)[UB], const float* base) {
#pragma unroll
    for (int u = 0; u < UB; ++u)
        asm volatile("global_load_dword %0, %1, off"
                     : "=v"(xr[u]) : "v"(base + (size_t)u * BATCH) : "memory");
}
#define BIND16(a) "+v"(a[0]),"+v"(a[1]),"+v"(a[2]),"+v"(a[3]),"+v"(a[4]), \
    "+v"(a[5]),"+v"(a[6]),"+v"(a[7]),"+v"(a[8]),"+v"(a[9]),"+v"(a[10]),   \
    "+v"(a[11]),"+v"(a[12]),"+v"(a[13]),"+v"(a[14]),"+v"(a[15])
__device__ __forceinline__ void wait1_bind(float (&xr)[UB]) {
    asm volatile("s_waitcnt vmcnt(1)" : BIND16(xr) :: "memory");
}
__device__ __forceinline__ void wait0_bind(float (&xr)[UB]) {
    asm volatile("s_waitcnt vmcnt(0)" : BIND16(xr) :: "memory");
}

// ---- R15: R10 step, 2-chain + wrap extraction -----------------------------
// Occupancy-cadence model (fit R8-R14): each instr occupies issue for its
// rate-cycles (VALU 4, trans 16, ds 8, vmem 4; nops/waits free) @ ~2.05 GHz.
// Latency/dep-depth irrelevant (R9), interleave gains nothing (R11), trans
// is un-hideable pipe occupancy. Only lever: weighted op count per step.
// R15 cuts vs R10: 3-chain -> 2-chain (-1 add), per-16 finisher -> wrap
// extraction (R14-harness-proven mapping; row t0+15 extracted by next
// block's U=0, final row 4095 by one post-loop finisher).
// Spacings all R8/R10-proven: rcp->plain-r dist3+nop, rcp->DPP-r dist4,
// acc RAW dist2 (R8), combine reads c1 at dist1 (R10), c0->exp dist1,
// exp->add1 dist2+nop, add1->rcp dist2, c0->pk dist3+nop (R10).
#define STEP_HEAD \
    "v_fma_f32 %[c0], %[wih2], %[x], %[bj2]\n\t"                                   /* 1 */ \
    "v_fmac_f32 %[c0], %[r], %[w0]\n\t"                                            /* 2 plain r, dist3 from rcp */ \
    "v_mul_f32_dpp %[c1], %[r], %[w1] row_ror:1 row_mask:0xf bank_mask:0xf\n\t"    /* 3 DPP r, dist4 */ \
    "v_fmac_f32_dpp %[c0], %[r], %[w2] row_ror:2 row_mask:0xf bank_mask:0xf\n\t"   /* 4 */ \
    "v_fmac_f32_dpp %[c1], %[r], %[w3] row_ror:3 row_mask:0xf bank_mask:0xf\n\t"   /* 5 */ \
    "v_fmac_f32_dpp %[c0], %[r], %[w4] row_ror:4 row_mask:0xf bank_mask:0xf\n\t"   /* 6 */ \
    "v_fmac_f32_dpp %[c1], %[r], %[w5] row_ror:5 row_mask:0xf bank_mask:0xf\n\t"   /* 7 */ \
    "v_fmac_f32_dpp %[c0], %[r], %[w6] row_ror:6 row_mask:0xf bank_mask:0xf\n\t"   /* 8 */ \
    "v_fmac_f32_dpp %[c1], %[r], %[w7] row_ror:7 row_mask:0xf bank_mask:0xf\n\t"   /* 9 */ \
    "v_fmac_f32_dpp %[c0], %[r], %[w8] row_ror:8 row_mask:0xf bank_mask:0xf\n\t"   /* 10 */ \
    "v_fmac_f32_dpp %[c1], %[r], %[w9] row_ror:9 row_mask:0xf bank_mask:0xf\n\t"   /* 11 */ \
    "v_fmac_f32_dpp %[c0], %[r], %[w10] row_ror:10 row_mask:0xf bank_mask:0xf\n\t" /* 12 */ \
    "v_fmac_f32_dpp %[c1], %[r], %[w11] row_ror:11 row_mask:0xf bank_mask:0xf\n\t" /* 13 */ \
    "v_fmac_f32_dpp %[c0], %[r], %[w12] row_ror:12 row_mask:0xf bank_mask:0xf\n\t" /* 14 */ \
    "v_fmac_f32_dpp %[c1], %[r], %[w13] row_ror:13 row_mask:0xf bank_mask:0xf\n\t" /* 15 */ \
    "v_fmac_f32_dpp %[c0], %[r], %[w14] row_ror:14 row_mask:0xf bank_mask:0xf\n\t" /* 16 */ \
    "v_fmac_f32_dpp %[c1], %[r], %[w15] row_ror:15 row_mask:0xf bank_mask:0xf\n\t" /* 17 */ \
    "v_add_f32 %[c0], %[c0], %[c1]\n\t"                                            /* 18 c1 dist1 (R10-proven) */ \
    "v_exp_f32 %[ex], %[c0]\n\t"                                                   /* 19 c0 dist1 (R10-proven) */ \
    "s_nop 0\n\t"                                                                  /* trans-use wait */ \
    "v_add_f32 %[ex], 1.0, %[ex]\n\t"                                              /* 20 */

#define STEP_TAIL \
    "v_rcp_f32 %[r], %[ex]\n\t"                                                    /* 22 ex dist2 (R10-proven) */ \
    "s_nop 0"                                                                      /* trans-use wait */

// pk extraction (slot 21, c0 dist3+nop from slot 18 — R10-proven spacing):
// lane (U-1)&15 <- lane 10's c0 via row_ror:(U+5)&15.
#define PKDPP(N) "v_fmac_f32_dpp %[pk], %[c0], %[m] row_ror:" #N " row_mask:0xf bank_mask:0xf\n\t"
#define PKPLAIN  "v_fmac_f32 %[pk], %[c0], %[m]\n\t"

#define DEF_STEP(SUF, PKLINE_) \
__device__ __forceinline__ void step_##SUF(float& r, float& pk, float x, \
        float wih2, float bj2, float m, const float (&w)[16]) { \
    float c0, c1, ex; \
    asm volatile( STEP_HEAD PKLINE_ STEP_TAIL \
        : [c0]"=&v"(c0), [c1]"=&v"(c1), [ex]"=&v"(ex), \
          [r]"+v"(r), [pk]"+v"(pk) \
        : [x]"v"(x), [wih2]"v"(wih2), [bj2]"v"(bj2), [m]"v"(m), \
          [w0]"v"(w[0]),  [w1]"v"(w[1]),  [w2]"v"(w[2]),  [w3]"v"(w[3]), \
          [w4]"v"(w[4]),  [w5]"v"(w[5]),  [w6]"v"(w[6]),  [w7]"v"(w[7]), \
          [w8]"v"(w[8]),  [w9]"v"(w[9]),  [w10]"v"(w[10]),[w11]"v"(w[11]), \
          [w12]"v"(w[12]),[w13]"v"(w[13]),[w14]"v"(w[14]),[w15]"v"(w[15])); \
}

DEF_STEP(r0,  PKPLAIN)
DEF_STEP(r1,  PKDPP(1))
DEF_STEP(r2,  PKDPP(2))
DEF_STEP(r3,  PKDPP(3))
DEF_STEP(r4,  PKDPP(4))
DEF_STEP(r5,  PKDPP(5))
DEF_STEP(r6,  PKDPP(6))
DEF_STEP(r7,  PKDPP(7))
DEF_STEP(r8,  PKDPP(8))
DEF_STEP(r9,  PKDPP(9))
DEF_STEP(r10, PKDPP(10))
DEF_STEP(r11, PKDPP(11))
DEF_STEP(r12, PKDPP(12))
DEF_STEP(r13, PKDPP(13))
DEF_STEP(r14, PKDPP(14))
DEF_STEP(r15, PKDPP(15))

// Dispatcher: step U extracts out-row t0+U-1 to lane (U-1)&15 via
// ROT=(U+5)&15 (R10/R14-proven). U=0 wraps: mask km[15] -> lane 15 carries
// y_{t0-1} (stored this block; skipped for t0=0). No per-16 finisher.
template<int U>
__device__ __forceinline__ void step_u(float& r, float& pk, float x,
                                       float wih2, float bj2,
                                       const float (&km)[16],
                                       const float (&w)[16]) {
    constexpr int ROT = (U + 5) & 15;
    const float m = km[(U + 15) & 15];
    if constexpr (ROT == 0)       step_r0 (r, pk, x, wih2, bj2, m, w);
    else if constexpr (ROT == 1)  step_r1 (r, pk, x, wih2, bj2, m, w);
    else if constexpr (ROT == 2)  step_r2 (r, pk, x, wih2, bj2, m, w);
    else if constexpr (ROT == 3)  step_r3 (r, pk, x, wih2, bj2, m, w);
    else if constexpr (ROT == 4)  step_r4 (r, pk, x, wih2, bj2, m, w);
    else if constexpr (ROT == 5)  step_r5 (r, pk, x, wih2, bj2, m, w);
    else if constexpr (ROT == 6)  step_r6 (r, pk, x, wih2, bj2, m, w);
    else if constexpr (ROT == 7)  step_r7 (r, pk, x, wih2, bj2, m, w);
    else if constexpr (ROT == 8)  step_r8 (r, pk, x, wih2, bj2, m, w);
    else if constexpr (ROT == 9)  step_r9 (r, pk, x, wih2, bj2, m, w);
    else if constexpr (ROT == 10) step_r10(r, pk, x, wih2, bj2, m, w);
    else if constexpr (ROT == 11) step_r11(r, pk, x, wih2, bj2, m, w);
    else if constexpr (ROT == 12) step_r12(r, pk, x, wih2, bj2, m, w);
    else if constexpr (ROT == 13) step_r13(r, pk, x, wih2, bj2, m, w);
    else if constexpr (ROT == 14) step_r14(r, pk, x, wih2, bj2, m, w);
    else                          step_r15(r, pk, x, wih2, bj2, m, w);
}

template<int U>
__device__ __forceinline__ void run16(float& r, float& pk, const float (&xr)[UB],
                                      float wih2, float bj2,
                                      const float (&km)[16],
                                      const float (&w)[16]) {
    if constexpr (U < UB) {
        step_u<U>(r, pk, xr[U], wih2, bj2, km, w);
        run16<U + 1>(r, pk, xr, wih2, bj2, km, w);
    }
}

// Post-loop finisher (R8-proven): rotational butterfly -> every lane holds
// y_{4095}-C0; keep on lane 0 via mask.
__device__ __forceinline__ void finish_reduce(float r, float& p, float& pk,
                                              float wo2, float m0) {
    asm volatile(
        "v_mul_f32 %[p], %[wo2], %[r]\n\t"
        "s_nop 1\n\t"
        "v_add_f32_dpp %[p], %[p], %[p] row_ror:8 row_mask:0xf bank_mask:0xf\n\t"
        "s_nop 1\n\t"
        "v_add_f32_dpp %[p], %[p], %[p] row_ror:4 row_mask:0xf bank_mask:0xf\n\t"
        "s_nop 1\n\t"
        "v_add_f32_dpp %[p], %[p], %[p] row_ror:2 row_mask:0xf bank_mask:0xf\n\t"
        "s_nop 1\n\t"
        "v_add_f32_dpp %[p], %[p], %[p] row_ror:1 row_mask:0xf bank_mask:0xf\n\t"
        "s_nop 1\n\t"
        "v_fmac_f32 %[pk], %[p], %[m]"
        : [p]"+v"(p), [pk]"+v"(pk)
        : [r]"v"(r), [wo2]"v"(wo2), [m]"v"(m0));
}

__global__ __launch_bounds__(64, 1) void rnn_kernel(
    const float* __restrict__ x,
    const float* __restrict__ h0,
    const float* __restrict__ W_ih,
    const float* __restrict__ b_ih,
    const float* __restrict__ W_hh,
    const float* __restrict__ b_hh,
    const float* __restrict__ W_out,
    const float* __restrict__ b_out,
    float* __restrict__ out)
{
    const int tid = threadIdx.x;            // 0..63
    const int j   = tid & 15;               // lane-in-group; j<10 owns dim j
    const int b   = (blockIdx.x << 2) + (tid >> 4);
    const bool jv = (j < HID);
    const int jc  = jv ? j : 0;

    const float CC = 2.88539008177792681472f;   // 2*log2(e)

    const float wih = jv ? W_ih[jc] : 0.0f;
    const float bj  = jv ? (b_ih[jc] + b_hh[jc]) : 0.0f;
    const float wo  = jv ? W_out[jc] : 0.0f;

    float wsh[16];
    float wsum = 0.0f;
#pragma unroll
    for (int N = 0; N < 16; ++N) {
        const int k = (j - N) & 15;
        wsh[N] = (jv && k < HID) ? W_hh[jc * HID + k] : 0.0f;
        wsum += wsh[N];
    }

    // r-form folded constants: a' = C*a with h = 1-2r absorbed.
    const float wih2 = CC * wih;                 // 0 for j>=10
    const float bj2  = CC * (bj + wsum);         // 0 for j>=10
    // Lanes 0..9: -2C*W_hh rows. Lane 10: output row, unscaled (-2*wo), so
    // its accumulated c0 = y - C0. Lanes 11..15: 0.
    float w2[16];
#pragma unroll
    for (int N = 0; N < 16; ++N) {
        if (jv) {
            w2[N] = -2.0f * CC * wsh[N];
        } else if (j == 10) {
            const int k = (10 - N) & 15;
            w2[N] = (k < HID) ? (-2.0f * W_out[k]) : 0.0f;
        } else {
            w2[N] = 0.0f;
        }
    }
    const float wo2 = -2.0f * wo;                // post-loop finisher only
    float c0sum = b_out[0];
#pragma unroll
    for (int k = 0; k < HID; ++k) c0sum += W_out[k];   // C0 = sum(wo) + bo

    // Keep-masks.
    float km[16];
#pragma unroll
    for (int i = 0; i < 16; ++i) km[i] = (j == i) ? 1.0f : 0.0f;

    // r_0 = (1 - h_0)/2 ; idle lanes h0=0 -> r=0.5 (their fixed point).
    float rval = fmaf(-0.5f, jv ? h0[b * HID + jc] : 0.0f, 0.5f);
    float pk = 0.0f;

    const float* xb = x + b;
    float xA[UB], xB[UB];

    issue16(xA, xb);
    wait0_bind(xA);

    for (int t0 = 0; t0 < T_STEPS; t0 += 2 * UB) {
        // ---- half 1: consume xA, prefetch xB ----
        wait1_bind(xA);
        issue16(xB, xb + (size_t)(t0 + UB) * BATCH);
        run16<0>(rval, pk, xA, wih2, bj2, km, w2);
        // Wrap-store: lane j holds y_{t0+j} (j<15); lane 15 holds y_{t0-1}.
        {
            const int tj = t0 + ((j == 15) ? -1 : j);
            if (tj >= 0) out[(size_t)tj * BATCH + b] = pk + c0sum;
        }
        pk = 0.0f;

        // ---- half 2: consume xB, prefetch xA ----
        wait1_bind(xB);
        const float* xsrc = (t0 + 2 * UB < T_STEPS)
                          ? (xb + (size_t)(t0 + 2 * UB) * BATCH) : xb;
        issue16(xA, xsrc);
        run16<0>(rval, pk, xB, wih2, bj2, km, w2);
        {
            const int t1 = t0 + UB;
            const int tj = t1 + ((j == 15) ? -1 : j);
            out[(size_t)tj * BATCH + b] = pk + c0sum;
        }
        pk = 0.0f;
    }

    // Drain the final speculative xA reload while registers are still bound
    // (async-clobber hazard, R6 post-mortem).
    wait0_bind(xA);

    // Final output row t=4095 from final r (R14-proven pattern).
    float p = 0.0f, pk2 = 0.0f;
    finish_reduce(rval, p, pk2, wo2, km[0]);
    if (j == 0) out[(size_t)(T_STEPS - 1) * BATCH + b] = pk2 + c0sum;

    // h_last: h = 1 - 2r
    if (jv) out[(size_t)T_STEPS * BATCH + (size_t)b * HID + j]
                = fmaf(-2.0f, rval, 1.0f);
}

extern "C" void kernel_launch(void* const* d_in, const int* in_sizes, int n_in,
                              void* d_out, int out_size, void* d_ws, size_t ws_size,
                              hipStream_t stream) {
    const float* x     = (const float*)d_in[0];
    const float* h0    = (const float*)d_in[1];
    const float* W_ih  = (const float*)d_in[2];
    const float* b_ih  = (const float*)d_in[3];
    const float* W_hh  = (const float*)d_in[4];
    const float* b_hh  = (const float*)d_in[5];
    const float* W_out = (const float*)d_in[6];
    const float* b_out = (const float*)d_in[7];

    rnn_kernel<<<BATCH / 4, 64, 0, stream>>>(
        x, h0, W_ih, b_ih, W_hh, b_hh, W_out, b_out, (float*)d_out);
}